// Round 5
// baseline (152.732 us; speedup 1.0000x reference)
//
#include <hip/hip_runtime.h>

#define CH 128

typedef unsigned int uint;
typedef unsigned short ushort;
typedef __attribute__((ext_vector_type(8))) short bf16x8;
typedef __attribute__((ext_vector_type(4))) float f32x4;

__device__ inline ushort f2bf(float f) {
    uint u = __float_as_uint(f);
    u += 0x7fffu + ((u >> 16) & 1u);     // RNE
    return (ushort)(u >> 16);
}
__device__ inline float blo(uint v) { return __uint_as_float(v << 16); }
__device__ inline float bhi(uint v) { return __uint_as_float(v & 0xffff0000u); }
__device__ inline uint pk(float a, float b) { return (uint)f2bf(a) | ((uint)f2bf(b) << 16); }

// ---------------- merged: weight transpose-convert (blocks 0..127) + deg zero (rest) ----------------
__global__ void k_prolog(const float* __restrict__ W00, const float* __restrict__ W01,
                         const float* __restrict__ W10, const float* __restrict__ W11,
                         uint* __restrict__ Wt0, uint* __restrict__ Wt1,
                         int* __restrict__ deg, int N) {
    if (blockIdx.x < 128) {
        int tid = blockIdx.x * 256 + threadIdx.x;      // 0..32767
        int which = tid >> 14;
        int t = tid & 16383;
        int col = t & 127, kp = t >> 7;
        int k = kp * 2;
        const float* W = (which == 0) ? ((k < 128) ? W00 : W01) : ((k < 128) ? W10 : W11);
        uint* Wt = (which == 0) ? Wt0 : Wt1;
        int kk = k & 127;
        float f0 = W[(size_t)kk * 128 + col];
        float f1 = W[(size_t)(kk + 1) * 128 + col];
        Wt[(size_t)col * 128 + kp] = pk(f0, f1);
    } else {
        int i = (blockIdx.x - 128) * 256 + threadIdx.x;
        if (i < N) deg[i] = 0;
    }
}

// ---------------- degree + per-edge slot ----------------
__global__ void k_deg(const int* __restrict__ row, int* __restrict__ deg,
                      int* __restrict__ pos, int E) {
    int e = blockIdx.x * blockDim.x + threadIdx.x;
    if (e < E) pos[e] = atomicAdd(&deg[row[e]], 1);
}

// ---------------- x convert (+ inline dinv compute/store) ----------------
__global__ void k_cvt_x(const float4* __restrict__ X, const int* __restrict__ deg,
                        float* __restrict__ dinv,
                        uint2* __restrict__ Xb, uint2* __restrict__ Xsb, int n4) {
    int i = blockIdx.x * 256 + threadIdx.x;
    if (i >= n4) return;
    int node = i >> 5;
    int d = deg[node];
    float s = (d > 0) ? rsqrtf((float)d) : 0.0f;
    if ((i & 31) == 0) dinv[node] = s;
    float4 v = X[i];
    Xb[i]  = make_uint2(pk(v.x, v.y), pk(v.z, v.w));
    Xsb[i] = make_uint2(pk(v.x * s, v.y * s), pk(v.z * s, v.w * s));
}

// ---------------- rowStart: self-computed prefix base + in-block scan ----------------
__global__ void k_rowstart(const int* __restrict__ deg, int* __restrict__ rowStart, int N) {
    __shared__ int s[256];
    const int base0 = blockIdx.x * 256;
    // sum deg[0..base0) strided
    int part = 0;
    for (int t = threadIdx.x; t < base0; t += 256) part += deg[t];
    s[threadIdx.x] = part;
    __syncthreads();
    for (int off = 128; off > 0; off >>= 1) {
        if (threadIdx.x < off) s[threadIdx.x] += s[threadIdx.x + off];
        __syncthreads();
    }
    const int base = s[0];
    __syncthreads();
    int i = base0 + threadIdx.x;
    int v = (i < N) ? deg[i] : 0;
    s[threadIdx.x] = v;
    __syncthreads();
    for (int off = 1; off < 256; off <<= 1) {
        int t = (threadIdx.x >= off) ? s[threadIdx.x - off] : 0;
        __syncthreads();
        s[threadIdx.x] += t;
        __syncthreads();
    }
    if (i < N) {
        int incl = s[threadIdx.x];
        rowStart[i] = base + incl - v;
        if (i == N - 1) rowStart[N] = base + incl;
    }
}

// ---------------- CSR fill: pure scatter, no atomics ----------------
__global__ void k_fill(const int* __restrict__ row, const int* __restrict__ col,
                       const int* __restrict__ rowStart, const int* __restrict__ pos,
                       int* __restrict__ csr, int E) {
    int e = blockIdx.x * blockDim.x + threadIdx.x;
    if (e < E) csr[rowStart[row[e]] + pos[e]] = col[e];
}

// ---------------- SpMM: Ob[i] = bf16( -dinv[i] * sum_j Xs[j] ) ----------------
// 16 lanes per row, lane owns uint4 (8 channels). Unroll 8 -> 8 outstanding 256B gathers/group.
__global__ __launch_bounds__(256) void k_spmm(const uint4* __restrict__ Xs,
                                              const float* __restrict__ dinv,
                                              const int* __restrict__ rowStart,
                                              const int* __restrict__ csr,
                                              uint4* __restrict__ Ob, int N) {
    int r = (int)((blockIdx.x * 256 + threadIdx.x) >> 4);
    int l = threadIdx.x & 15;
    if (r >= N) return;
    int s = rowStart[r], e = rowStart[r + 1];
    float a0 = 0.f, a1 = 0.f, a2 = 0.f, a3 = 0.f;
    float a4 = 0.f, a5 = 0.f, a6 = 0.f, a7 = 0.f;
    int k = s;
    for (; k + 8 <= e; k += 8) {
        int j0 = csr[k + 0], j1 = csr[k + 1], j2 = csr[k + 2], j3 = csr[k + 3];
        int j4 = csr[k + 4], j5 = csr[k + 5], j6 = csr[k + 6], j7 = csr[k + 7];
        uint4 v0 = Xs[(size_t)j0 * 16 + l];
        uint4 v1 = Xs[(size_t)j1 * 16 + l];
        uint4 v2 = Xs[(size_t)j2 * 16 + l];
        uint4 v3 = Xs[(size_t)j3 * 16 + l];
        uint4 v4 = Xs[(size_t)j4 * 16 + l];
        uint4 v5 = Xs[(size_t)j5 * 16 + l];
        uint4 v6 = Xs[(size_t)j6 * 16 + l];
        uint4 v7 = Xs[(size_t)j7 * 16 + l];
        a0 += (blo(v0.x) + blo(v1.x)) + (blo(v2.x) + blo(v3.x)) + (blo(v4.x) + blo(v5.x)) + (blo(v6.x) + blo(v7.x));
        a1 += (bhi(v0.x) + bhi(v1.x)) + (bhi(v2.x) + bhi(v3.x)) + (bhi(v4.x) + bhi(v5.x)) + (bhi(v6.x) + bhi(v7.x));
        a2 += (blo(v0.y) + blo(v1.y)) + (blo(v2.y) + blo(v3.y)) + (blo(v4.y) + blo(v5.y)) + (blo(v6.y) + blo(v7.y));
        a3 += (bhi(v0.y) + bhi(v1.y)) + (bhi(v2.y) + bhi(v3.y)) + (bhi(v4.y) + bhi(v5.y)) + (bhi(v6.y) + bhi(v7.y));
        a4 += (blo(v0.z) + blo(v1.z)) + (blo(v2.z) + blo(v3.z)) + (blo(v4.z) + blo(v5.z)) + (blo(v6.z) + blo(v7.z));
        a5 += (bhi(v0.z) + bhi(v1.z)) + (bhi(v2.z) + bhi(v3.z)) + (bhi(v4.z) + bhi(v5.z)) + (bhi(v6.z) + bhi(v7.z));
        a6 += (blo(v0.w) + blo(v1.w)) + (blo(v2.w) + blo(v3.w)) + (blo(v4.w) + blo(v5.w)) + (blo(v6.w) + blo(v7.w));
        a7 += (bhi(v0.w) + bhi(v1.w)) + (bhi(v2.w) + bhi(v3.w)) + (bhi(v4.w) + bhi(v5.w)) + (bhi(v6.w) + bhi(v7.w));
    }
    for (; k + 2 <= e; k += 2) {
        int j0 = csr[k + 0], j1 = csr[k + 1];
        uint4 v0 = Xs[(size_t)j0 * 16 + l];
        uint4 v1 = Xs[(size_t)j1 * 16 + l];
        a0 += blo(v0.x) + blo(v1.x);  a1 += bhi(v0.x) + bhi(v1.x);
        a2 += blo(v0.y) + blo(v1.y);  a3 += bhi(v0.y) + bhi(v1.y);
        a4 += blo(v0.z) + blo(v1.z);  a5 += bhi(v0.z) + bhi(v1.z);
        a6 += blo(v0.w) + blo(v1.w);  a7 += bhi(v0.w) + bhi(v1.w);
    }
    if (k < e) {
        int j = csr[k];
        uint4 v = Xs[(size_t)j * 16 + l];
        a0 += blo(v.x); a1 += bhi(v.x); a2 += blo(v.y); a3 += bhi(v.y);
        a4 += blo(v.z); a5 += bhi(v.z); a6 += blo(v.w); a7 += bhi(v.w);
    }
    float sc = -dinv[r];
    uint4 o;
    o.x = pk(a0 * sc, a1 * sc);
    o.y = pk(a2 * sc, a3 * sc);
    o.z = pk(a4 * sc, a5 * sc);
    o.w = pk(a6 * sc, a7 * sc);
    Ob[(size_t)r * 16 + l] = o;
}

// ---------------- MFMA GEMM: out = epi( [A1|A2] @ Wt^T + bias ) ----------------
__global__ __launch_bounds__(512) void k_gemm_mfma(const uint* __restrict__ A1,
                                                   const uint* __restrict__ A2,
                                                   const uint* __restrict__ Wt,
                                                   const float* __restrict__ bias,
                                                   const float* __restrict__ xres,
                                                   const float* __restrict__ dinv,
                                                   void* __restrict__ outp,
                                                   uint* __restrict__ outs,
                                                   int N, int mode) {
    __shared__ uint AsU[2][128 * 20];
    __shared__ uint WsU[2][128 * 20];

    const int tid = threadIdx.x;
    const int lane = tid & 63;
    const int wid = tid >> 6;
    const int wr = wid >> 1;
    const int wc = wid & 1;
    const int row0 = blockIdx.x * 128;
    const int l16 = lane & 15;
    const int lk = lane >> 4;

    f32x4 acc[2][4];
    #pragma unroll
    for (int m = 0; m < 2; m++)
        #pragma unroll
        for (int n = 0; n < 4; n++)
            acc[m][n] = (f32x4){0.f, 0.f, 0.f, 0.f};

    const int sr = tid >> 2;
    const int sc4 = tid & 3;
    const uint4* A1p = (const uint4*)A1;
    const uint4* A2p = (const uint4*)A2;
    const uint4* Wtp = (const uint4*)Wt;
    const int arow = min(row0 + sr, N - 1);

    uint4 ga, gw;
    ga = A1p[(size_t)arow * 16 + sc4];
    gw = Wtp[(size_t)sr * 32 + sc4];
    *(uint4*)&AsU[0][sr * 20 + sc4 * 4] = ga;
    *(uint4*)&WsU[0][sr * 20 + sc4 * 4] = gw;
    __syncthreads();

    for (int t = 0; t < 8; ++t) {
        const int cur = t & 1;
        if (t < 7) {
            const int k0 = (t + 1) * 32;
            const uint4* Ap = (k0 < 128) ? A1p : A2p;
            const int kk = k0 & 127;
            ga = Ap[(size_t)arow * 16 + (kk >> 3) + sc4];
            gw = Wtp[(size_t)sr * 32 + (k0 >> 3) + sc4];
        }

        bf16x8 bfr[4];
        #pragma unroll
        for (int n = 0; n < 4; n++) {
            int col = wc * 64 + n * 16 + l16;
            bfr[n] = *(const bf16x8*)&WsU[cur][col * 20 + lk * 4];
        }
        #pragma unroll
        for (int m = 0; m < 2; m++) {
            int row = wr * 32 + m * 16 + l16;
            bf16x8 afr = *(const bf16x8*)&AsU[cur][row * 20 + lk * 4];
            #pragma unroll
            for (int n = 0; n < 4; n++)
                acc[m][n] = __builtin_amdgcn_mfma_f32_16x16x32_bf16(afr, bfr[n], acc[m][n], 0, 0, 0);
        }

        if (t < 7) {
            *(uint4*)&AsU[cur ^ 1][sr * 20 + sc4 * 4] = ga;
            *(uint4*)&WsU[cur ^ 1][sr * 20 + sc4 * 4] = gw;
            __syncthreads();
        }
    }

    if (mode == 0) {
        ushort* O = (ushort*)outp;
        ushort* S = (ushort*)outs;
        #pragma unroll
        for (int m = 0; m < 2; m++) {
            #pragma unroll
            for (int r = 0; r < 4; r++) {
                int rg = row0 + wr * 32 + m * 16 + lk * 4 + r;
                if (rg >= N) continue;
                float sc = dinv[rg];
                #pragma unroll
                for (int n = 0; n < 4; n++) {
                    const int col = wc * 64 + n * 16 + l16;
                    float v = fmaxf(acc[m][n][r] + bias[col], 0.f);
                    O[(size_t)rg * 128 + col] = f2bf(v);
                    S[(size_t)rg * 128 + col] = f2bf(v * sc);
                }
            }
        }
    } else {
        float* O = (float*)outp;
        #pragma unroll
        for (int m = 0; m < 2; m++) {
            #pragma unroll
            for (int r = 0; r < 4; r++) {
                int rg = row0 + wr * 32 + m * 16 + lk * 4 + r;
                if (rg >= N) continue;
                #pragma unroll
                for (int n = 0; n < 4; n++) {
                    const int col = wc * 64 + n * 16 + l16;
                    float v = fmaxf(acc[m][n][r] + bias[col], 0.f);
                    O[(size_t)rg * 128 + col] = 0.5f * (v + xres[(size_t)rg * 128 + col]);
                }
            }
        }
    }
}

extern "C" void kernel_launch(void* const* d_in, const int* in_sizes, int n_in,
                              void* d_out, int out_size, void* d_ws, size_t ws_size,
                              hipStream_t stream) {
    const float* x   = (const float*)d_in[0];
    const int*   ei  = (const int*)d_in[1];
    const float* W00 = (const float*)d_in[2];
    const float* W01 = (const float*)d_in[3];
    const float* b0  = (const float*)d_in[4];
    const float* W10 = (const float*)d_in[5];
    const float* W11 = (const float*)d_in[6];
    const float* b1  = (const float*)d_in[7];
    float* out = (float*)d_out;

    const int N = in_sizes[0] / CH;   // 40000
    const int E = in_sizes[1] / 2;    // 640000
    const int* row = ei;
    const int* col = ei + E;

    char* ws = (char*)d_ws;
    size_t off = 0;
    auto alloc = [&](size_t bytes) -> void* {
        void* p = ws + off;
        off += (bytes + 255) & ~(size_t)255;
        return p;
    };
    int*   deg      = (int*)alloc((size_t)N * 4);
    float* dinv     = (float*)alloc((size_t)N * 4);
    int*   rowStart = (int*)alloc((size_t)(N + 1) * 4);
    int*   pos      = (int*)alloc((size_t)E * 4);
    int*   csr      = (int*)alloc((size_t)E * 4);
    uint*  xb       = (uint*)alloc((size_t)N * 64 * 4);
    uint*  xsb      = (uint*)alloc((size_t)N * 64 * 4);
    uint*  Lb       = (uint*)alloc((size_t)N * 64 * 4);
    uint*  yb       = (uint*)alloc((size_t)N * 64 * 4);
    uint*  ysb      = (uint*)alloc((size_t)N * 64 * 4);
    uint*  Wt0      = (uint*)alloc(128 * 128 * 4);
    uint*  Wt1      = (uint*)alloc(128 * 128 * 4);

    const int nB = (N + 255) / 256;   // 157

    k_prolog<<<128 + nB, 256, 0, stream>>>(W00, W01, W10, W11, Wt0, Wt1, deg, N);
    k_deg<<<(E + 255) / 256, 256, 0, stream>>>(row, deg, pos, E);
    k_cvt_x<<<(N * 32 + 255) / 256, 256, 0, stream>>>((const float4*)x, deg, dinv,
                                                      (uint2*)xb, (uint2*)xsb, N * 32);
    k_rowstart<<<nB, 256, 0, stream>>>(deg, rowStart, N);
    k_fill<<<(E + 255) / 256, 256, 0, stream>>>(row, col, rowStart, pos, csr, E);

    const int gemmBlocks = (N + 127) / 128;
    const int spmmBlocks = (N * 16 + 255) / 256;

    // layer 1
    k_spmm<<<spmmBlocks, 256, 0, stream>>>((const uint4*)xsb, dinv, rowStart, csr,
                                           (uint4*)Lb, N);
    k_gemm_mfma<<<gemmBlocks, 512, 0, stream>>>(xb, Lb, Wt0, b0, nullptr, dinv,
                                                (void*)yb, ysb, N, 0);

    // layer 2
    k_spmm<<<spmmBlocks, 256, 0, stream>>>((const uint4*)ysb, dinv, rowStart, csr,
                                           (uint4*)Lb, N);
    k_gemm_mfma<<<gemmBlocks, 512, 0, stream>>>(yb, Lb, Wt1, b1, x, dinv,
                                                (void*)out, nullptr, N, 1);
}